// Round 9
// baseline (487.601 us; speedup 1.0000x reference)
//
#include <hip/hip_runtime.h>
#include <math.h>

// Problem constants
#define BB   64
#define CIN  16
#define LL   8192
#define CO   32
#define TCO  64
constexpr int T0n = 128;   // frames for n=64
constexpr int T1n = 32;    // frames for n=256
constexpr int F0n = 33;
constexpr int F1n = 129;
constexpr int PW0 = 48;    // padded S row dwords, head0 (= KT0*16)
constexpr int PW1 = 144;   // padded S row dwords, head1 (= KT1*16)

typedef unsigned int   uint32;
typedef unsigned short u16;
typedef __attribute__((ext_vector_type(8))) _Float16 half8;  // 8 f16 (4 VGPRs)
typedef __attribute__((ext_vector_type(4))) float    f32x4;  // MFMA accumulator
typedef __attribute__((ext_vector_type(4))) uint32   u32x4;

__device__ inline int imin(int a, int b) { return a < b ? a : b; }

__device__ inline uint32 pack2h(float a, float b) {
    _Float16 ha = (_Float16)a, hb = (_Float16)b;
    return ((uint32)(*(u16*)&hb) << 16) | (uint32)(*(u16*)&ha);
}

// sign-flip pattern (+,+,-,-,+,+,-,-) over a half8 B-frag: k2 = 8a+j -> f = 4a+(j>>1),
// (-1)^f over j flips j=2,3,6,7 = dwords 1 and 3.  Used for W row symmetry:
// W[m+N/2][k2] = (-1)^{f(k2)} * W[m][k2].  (correctness-proven, 468us run)
__device__ inline half8 flip_pm(half8 v) {
    u32x4 u;
    __builtin_memcpy(&u, &v, 16);
    u.y ^= 0x80008000u;
    u.w ^= 0x80008000u;
    half8 r;
    __builtin_memcpy(&r, &u, 16);
    return r;
}

// ---------------- STFT as GEMM: spec[t][j] = sum_k X[t][k] * D[k][j] -----------
template<int N, int F, int TFR, int NTILES, int KTT, int MT_W, int NT_W,
         int NT_STRIDE, bool MT_SPLIT>
__global__ __launch_bounds__(256)
void stft_mfma_kernel(const float* __restrict__ x,
                      const u16* __restrict__ dhi, const u16* __restrict__ dlo,
                      float* __restrict__ p) {
    constexpr int PADN = N + 8;            // +16B row pad -> 2-way LDS alias (free)
    __shared__ __align__(16) u16 Xhi[TFR * PADN];
    __shared__ __align__(16) u16 Xlo[TFR * PADN];
    int bc = blockIdx.x;                   // b*CIN + c
    const float* xrow = x + (size_t)bc * LL;

    // reflected edge (row 0, colk < N/2): scalar
    for (int i = threadIdx.x; i < N / 2; i += 256) {
        float v = xrow[N / 2 - i];
        _Float16 h = (_Float16)v;
        Xhi[i] = *(u16*)&h;
        _Float16 l = (_Float16)(v - (float)h);
        Xlo[i] = *(u16*)&l;
    }
    // bulk: float4 loads, uint2 LDS stores (G13 vectorization)
    for (int i4 = N / 8 + threadIdx.x; i4 < TFR * N / 4; i4 += 256) {
        int i = 4 * i4;
        int row = i / N, colk = i - row * N;   // N pow2 -> shifts
        float4 v = *(const float4*)&xrow[i - N / 2];
        _Float16 h0 = (_Float16)v.x, h1 = (_Float16)v.y,
                 h2 = (_Float16)v.z, h3 = (_Float16)v.w;
        uint2 hv, lv;
        hv.x = ((uint32)(*(u16*)&h1) << 16) | (uint32)(*(u16*)&h0);
        hv.y = ((uint32)(*(u16*)&h3) << 16) | (uint32)(*(u16*)&h2);
        lv.x = pack2h(v.x - (float)h0, v.y - (float)h1);
        lv.y = pack2h(v.z - (float)h2, v.w - (float)h3);
        *(uint2*)&Xhi[row * PADN + colk] = hv;
        *(uint2*)&Xlo[row * PADN + colk] = lv;
    }
    __syncthreads();

    int lane = threadIdx.x & 63, w = threadIdx.x >> 6;
    int col = lane & 15, quad = lane >> 4;
    f32x4 acc[MT_W][NT_W];
    #pragma unroll
    for (int mi = 0; mi < MT_W; ++mi)
        #pragma unroll
        for (int nj = 0; nj < NT_W; ++nj) {
            f32x4 z = {0.f, 0.f, 0.f, 0.f};
            acc[mi][nj] = z;
        }

    for (int kt = 0; kt < KTT; ++kt) {
        half8 ah[MT_W], al[MT_W];
        #pragma unroll
        for (int mi = 0; mi < MT_W; ++mi) {
            int mt = MT_SPLIT ? (w * MT_W + mi) : mi;
            int t  = mt * 16 + col;
            ah[mi] = *(const half8*)&Xhi[t * PADN + kt * 32 + quad * 8];
            al[mi] = *(const half8*)&Xlo[t * PADN + kt * 32 + quad * 8];
        }
        #pragma unroll
        for (int nj = 0; nj < NT_W; ++nj) {
            int nt = MT_SPLIT ? nj : (w + nj * NT_STRIDE);
            if (nt < NTILES) {
                half8 bh = ((const half8*)dhi)[(nt * KTT + kt) * 64 + lane];
                half8 bl = ((const half8*)dlo)[(nt * KTT + kt) * 64 + lane];
                #pragma unroll
                for (int mi = 0; mi < MT_W; ++mi) {
                    acc[mi][nj] = __builtin_amdgcn_mfma_f32_16x16x32_f16(ah[mi], bh, acc[mi][nj], 0, 0, 0);
                    acc[mi][nj] = __builtin_amdgcn_mfma_f32_16x16x32_f16(ah[mi], bl, acc[mi][nj], 0, 0, 0);
                    acc[mi][nj] = __builtin_amdgcn_mfma_f32_16x16x32_f16(al[mi], bh, acc[mi][nj], 0, 0, 0);
                }
            }
        }
    }

    int b = bc / CIN, c = bc % CIN;
    #pragma unroll
    for (int mi = 0; mi < MT_W; ++mi) {
        int mt = MT_SPLIT ? (w * MT_W + mi) : mi;
        #pragma unroll
        for (int nj = 0; nj < NT_W; ++nj) {
            int nt = MT_SPLIT ? nj : (w + nj * NT_STRIDE);
            if (nt < NTILES) {
                int j = nt * 16 + col;
                if (j < 2 * F) {
                    int t0 = mt * 16 + quad * 4;
                    f32x4 a = acc[mi][nj];
                    #pragma unroll
                    for (int r = 0; r < 4; ++r) {
                        p[(((size_t)b * TFR + t0 + r) * CIN + c) * (2 * F) + j] = a[r];
                    }
                }
            }
        }
    }
}

// ---------------- init: STFT D tables, B-fragment order, split fp16 ------------
__global__ __launch_bounds__(256)
void init_d_kernel(u16* __restrict__ dhi0, u16* __restrict__ dlo0,
                   u16* __restrict__ dhi1, u16* __restrict__ dlo1) {
    int idx = blockIdx.x * 256 + threadIdx.x;
    constexpr int SZ0 = 5 * 2 * 64 * 8;    // 5120
    constexpr int SZ1 = 17 * 8 * 64 * 8;   // 69632
    int N, F, KTT, id; u16 *dh, *dl;
    if (idx < SZ0)            { N = 64;  F = F0n; KTT = 2; dh = dhi0; dl = dlo0; id = idx; }
    else if (idx < SZ0 + SZ1) { N = 256; F = F1n; KTT = 8; dh = dhi1; dl = dlo1; id = idx - SZ0; }
    else return;
    int jj   = id & 7;
    int lane = (id >> 3) & 63;
    int rest = id >> 9;
    int kt   = rest % KTT;
    int nt   = rest / KTT;
    int j = nt * 16 + (lane & 15);
    int k = kt * 32 + (lane >> 4) * 8 + jj;
    float v = 0.f;
    if (j < 2 * F) {
        int f = j >> 1;
        int u = (f * k) % N;
        double th = 6.283185307179586476925286766559 * (double)u / (double)N;
        v = (float)((j & 1) ? -sin(th) : cos(th));
    }
    _Float16 h = (_Float16)v;
    _Float16 l = (_Float16)(v - (float)h);
    dh[id] = *(u16*)&h;
    dl[id] = *(u16*)&l;
}

// ---------------- merge (attention over 4 sub-frames), in-place into p1 --------
__global__ __launch_bounds__(256)
void merge_kernel(const float2* __restrict__ p0, float2* __restrict__ p1,
                  const float* __restrict__ mkr, const float* __restrict__ mki,
                  const float* __restrict__ mbr, const float* __restrict__ mbi) {
    int idx = blockIdx.x * 256 + threadIdx.x;
    const int total = BB * T1n * CIN * F0n;
    if (idx >= total) return;
    int f0 = idx % F0n; int r1 = idx / F0n;
    int c  = r1 % CIN;  int r2 = r1 / CIN;
    int t1 = r2 % T1n;  int b  = r2 / T1n;
    float2 pm[4];
    #pragma unroll
    for (int r = 0; r < 4; ++r) {
        int t = t1 * 4 + r;
        pm[r] = p0[(((size_t)b * T0n + t) * CIN + c) * F0n + f0];
    }
    float mag[4], mx = -1e30f;
    #pragma unroll
    for (int s = 0; s < 4; ++s) {
        float atr = mbr[s], ati = mbi[s];
        #pragma unroll
        for (int r = 0; r < 4; ++r) {
            float kr = mkr[r * 4 + s], ki = mki[r * 4 + s];
            atr = fmaf(pm[r].x, kr, atr); atr = fmaf(-pm[r].y, ki, atr);
            ati = fmaf(pm[r].x, ki, ati); ati = fmaf(pm[r].y, kr, ati);
        }
        mag[s] = sqrtf(atr * atr + ati * ati);
        mx = fmaxf(mx, mag[s]);
    }
    float se = 0.f;
    #pragma unroll
    for (int s = 0; s < 4; ++s) { mag[s] = expf(mag[s] - mx); se += mag[s]; }
    float inv = 4.0f / se;                 // RATIO / sum
    float mr = 0.f, mi = 0.f;
    #pragma unroll
    for (int r = 0; r < 4; ++r) { mr = fmaf(pm[r].x, mag[r], mr); mi = fmaf(pm[r].y, mag[r], mi); }
    p1[(((size_t)b * T1n + t1) * CIN + c) * F1n + 4 * f0] = make_float2(mr * inv, mi * inv);
}

// ---------------- complex batch-norm stats, two-stage ---------------------------
__global__ __launch_bounds__(256)
void cbn_partial_kernel(const float2* __restrict__ p0, const float2* __restrict__ p1,
                        float4* __restrict__ part) {
    int blk  = blockIdx.x;                 // head*512 + b*8 + c8
    int c8   = blk & 7;
    int b    = (blk >> 3) & 63;
    int head = blk >> 9;
    int Nel  = head ? (T1n * CIN * F1n) : (T0n * CIN * F0n);
    const float2* base = head ? (p1 + (size_t)b * (T1n * CIN * F1n))
                              : (p0 + (size_t)b * (T0n * CIN * F0n));
    int chunk = (Nel + 7) / 8;
    int i0 = c8 * chunk, i1 = imin(i0 + chunk, Nel);
    float sr = 0.f, si = 0.f, s2 = 0.f;
    for (int i = i0 + threadIdx.x; i < i1; i += 256) {
        float2 v = base[i];
        sr += v.x; si += v.y;
        s2 = fmaf(v.x, v.x, s2); s2 = fmaf(v.y, v.y, s2);
    }
    __shared__ float red[3][256];
    red[0][threadIdx.x] = sr; red[1][threadIdx.x] = si; red[2][threadIdx.x] = s2;
    __syncthreads();
    for (int off = 128; off > 0; off >>= 1) {
        if (threadIdx.x < off) {
            red[0][threadIdx.x] += red[0][threadIdx.x + off];
            red[1][threadIdx.x] += red[1][threadIdx.x + off];
            red[2][threadIdx.x] += red[2][threadIdx.x + off];
        }
        __syncthreads();
    }
    if (threadIdx.x == 0)
        part[blk] = make_float4(red[0][0], red[1][0], red[2][0], 0.f);
}

__global__ __launch_bounds__(128)
void cbn_final_kernel(const float4* __restrict__ part,
                      const float* __restrict__ gamma, const float* __restrict__ beta,
                      float4* __restrict__ bn) {
    int hb = threadIdx.x;                  // 0..127 = head*64 + b
    float sr = 0.f, si = 0.f, s2 = 0.f;
    #pragma unroll
    for (int c = 0; c < 8; ++c) {
        float4 v = part[hb * 8 + c];
        sr += v.x; si += v.y; s2 += v.z;
    }
    int head = hb >> 6;
    int Nel  = head ? (T1n * CIN * F1n) : (T0n * CIN * F0n);
    float invN = 1.f / (float)Nel;
    float mur = sr * invN, mui = si * invN;
    float var = s2 * invN - mur * mur - mui * mui;
    float g = gamma[hb] * rsqrtf(var + 1e-5f);
    bn[hb] = make_float4(g, beta[hb] - mur * g, -mui * g, 0.f);
}

// ---------------- init: irfft twiddle matrix (HALF rows m < N/2), split fp16 ---
__global__ __launch_bounds__(256)
void init_w_kernel(u16* __restrict__ whi0, u16* __restrict__ wlo0,
                   u16* __restrict__ whi1, u16* __restrict__ wlo1) {
    int idx = blockIdx.x * 256 + threadIdx.x;
    constexpr int SZ0 = 2 * 3 * 64 * 8;    // 3072
    constexpr int SZ1 = 8 * 9 * 64 * 8;    // 36864
    int N, F, KT, id; u16 *dh, *dl;
    if (idx < SZ0)            { N = 64;  F = F0n; KT = 3; dh = whi0; dl = wlo0; id = idx; }
    else if (idx < SZ0 + SZ1) { N = 256; F = F1n; KT = 9; dh = whi1; dl = wlo1; id = idx - SZ0; }
    else return;
    int j    = id & 7;
    int lane = (id >> 3) & 63;
    int rest = id >> 9;
    int kt   = rest % KT;
    int mt   = rest / KT;
    int m  = mt * 16 + (lane & 15);        // m < N/2 only
    int k2 = kt * 32 + (lane >> 4) * 8 + j;
    float v = 0.f;
    if (k2 < 2 * F) {
        int f = k2 >> 1;
        double scale = (f == 0 || f == F - 1) ? (1024.0 / N) : (2048.0 / N);
        int u = (m * f) % N;
        double th = 6.283185307179586476925286766559 * (double)u / (double)N;
        v = (float)((k2 & 1) ? (-scale * sin(th)) : (scale * cos(th)));
    }
    _Float16 h = (_Float16)v;
    _Float16 l = (_Float16)(v - (float)h);
    dh[id] = *(u16*)&h;
    dl[id] = *(u16*)&l;
}

// ---------------- init: fk tables, layout i = o*F + f --------------------------
__global__ __launch_bounds__(256)
void init_fk_kernel(const float* __restrict__ r0, const float* __restrict__ i0,
                    const float* __restrict__ r1, const float* __restrict__ i1,
                    float4* __restrict__ q0, float4* __restrict__ q1,
                    float2* __restrict__ s0, float2* __restrict__ s1) {
    int idx = blockIdx.x * 256 + threadIdx.x;
    constexpr int NQ0 = 8 * F0n * 32;   // 8448
    constexpr int NQ1 = 8 * F1n * 32;   // 33024
    constexpr int NS0 = F0n * 32;       // 1056
    constexpr int NS1 = F1n * 32;       // 4128
    if (idx < NQ0) {
        int id = idx;
        int c2 = id / (F0n * 32); int rem = id % (F0n * 32);
        int o = rem / F0n, f = rem % F0n;
        int s = (f * CIN + 2 * c2) * CO + o;
        q0[id] = make_float4(r0[s], i0[s], r0[s + CO], i0[s + CO]);
    } else if (idx < NQ0 + NQ1) {
        int id = idx - NQ0;
        int c2 = id / (F1n * 32); int rem = id % (F1n * 32);
        int o = rem / F1n, f = rem % F1n;
        int s = (f * CIN + 2 * c2) * CO + o;
        q1[id] = make_float4(r1[s], i1[s], r1[s + CO], i1[s + CO]);
    } else if (idx < NQ0 + NQ1 + NS0) {
        int id = idx - NQ0 - NQ1;
        int o = id / F0n, f = id % F0n;
        float sr = 0.f, si = 0.f;
        for (int ci = 0; ci < CIN; ++ci) {
            int s = (f * CIN + ci) * CO + o;
            sr += r0[s]; si += i0[s];
        }
        s0[id] = make_float2(sr, si);
    } else if (idx < NQ0 + NQ1 + NS0 + NS1) {
        int id = idx - NQ0 - NQ1 - NS0;
        int o = id / F1n, f = id % F1n;
        float sr = 0.f, si = 0.f;
        for (int ci = 0; ci < CIN; ++ci) {
            int s = (f * CIN + ci) * CO + o;
            sr += r1[s]; si += i1[s];
        }
        s1[id] = make_float2(sr, si);
    }
}

// ---------------- einsum: weights-in-VGPR, t-chunked, SEPARATE launch per head --
// Round-8 lesson (rule #19): merging both heads into one kernel behind a runtime
// branch made regalloc drop to 32 VGPR and demote the kk[8] weight cache ->
// fkq re-loaded every tp iteration (152us, FETCH 109MB).  Keep per-head kernels
// (round-7 codegen, VGPR 44, kk resident).  f-chunks cover the FULL padded
// width PADW; threads with f >= F store zeros so irfft stages with float4.
template<int F, int TFR, int CH0, int PADW>
__global__ __launch_bounds__(256)
void einsum_kernel(const float2* __restrict__ p, const float4* __restrict__ fkq,
                   const float2* __restrict__ fks, const float4* __restrict__ bn,
                   uint32* __restrict__ Ghi, uint32* __restrict__ Glo) {
    constexpr int FCH = 8, TCH = 16;
    constexpr int FCO  = F * 32;
    constexpr int NFCH = PADW / FCH;
    constexpr int NTC  = TFR / TCH;
    __shared__ float2 xs[TCH][CIN][FCH];
    int blk  = blockIdx.x;
    int fch  = blk % NFCH;
    int rest = blk / NFCH;
    int tc   = rest % NTC;
    int b    = rest / NTC;
    int t0   = tc * TCH;
    int f0   = fch * FCH;
    int o    = threadIdx.x >> 3;       // 0..31
    int fl   = threadIdx.x & 7;        // 0..7
    int f    = f0 + fl;
    bool valid = f < F;
    int fc = valid ? f : F - 1;
    float4 kk[8];
    #pragma unroll
    for (int c2 = 0; c2 < 8; ++c2) kk[c2] = fkq[c2 * FCO + o * F + fc];  // coalesced
    float2 fv = fks[o * F + fc];
    float4 par = bn[(CH0 ? 1 : 0) * BB + b];   // (g, t_re, t_im, -)
    float base_re = fmaf(par.y, fv.x, -par.z * fv.y);
    float base_im = fmaf(par.y, fv.y,  par.z * fv.x);

    const float2* pb = p + (size_t)(b * TFR + t0) * CIN * F;
    for (int i = threadIdx.x; i < TCH * CIN * FCH; i += 256) {
        int fi = i & 7;                // FCH = 8
        int r  = i >> 3;               // t'*CIN + ci
        int ff = f0 + fi;
        ((float2*)xs)[i] = (ff < F) ? pb[(size_t)r * F + ff] : make_float2(0.f, 0.f);
    }
    __syncthreads();
    for (int tp = 0; tp < TCH; ++tp) {
        float re = 0.f, im = 0.f;
        #pragma unroll
        for (int c2 = 0; c2 < 8; ++c2) {
            float2 xa = xs[tp][2 * c2][fl];        // LDS broadcast
            float2 xb = xs[tp][2 * c2 + 1][fl];
            float4 kkc = kk[c2];
            re = fmaf(xa.x, kkc.x, re); re = fmaf(-xa.y, kkc.y, re);
            im = fmaf(xa.x, kkc.y, im); im = fmaf(xa.y, kkc.x, im);
            re = fmaf(xb.x, kkc.z, re); re = fmaf(-xb.y, kkc.w, re);
            im = fmaf(xb.x, kkc.w, im); im = fmaf(xb.y, kkc.z, im);
        }
        uint32 hv = 0, lv = 0;
        if (valid) {
            float res = fmaf(par.x, re, base_re) * 32.f;
            float ims = fmaf(par.x, im, base_im) * 32.f;
            _Float16 rh = (_Float16)res; _Float16 rl = (_Float16)(res - (float)rh);
            _Float16 ih = (_Float16)ims; _Float16 il = (_Float16)(ims - (float)ih);
            hv = ((uint32)(*(u16*)&ih) << 16) | (uint32)(*(u16*)&rh);
            lv = ((uint32)(*(u16*)&il) << 16) | (uint32)(*(u16*)&rl);
        }
        size_t d = ((size_t)(b * TFR + t0 + tp) * 32 + o) * PADW + f;
        Ghi[d] = hv;
        Glo[d] = lv;
    }
}

// ---------------- irfft body: per-frame block, float4 copy stage, W symmetry ---
// S rows are padded (zeros) to PADW dwords by einsum -> stage is a pure float4
// copy of 32 contiguous rows; no LDS zero-pad loop.  LDW = PADW+4 (bank spread).
template<int N, int F, int TFR, int CH0, int KT, int WMT, bool NTSPLIT>
__device__ __forceinline__ void irfft_body(
        int blk, uint32* bufA,
        const uint32* __restrict__ Ghi, const uint32* __restrict__ Glo,
        const u16* __restrict__ whi, const u16* __restrict__ wlo,
        const float* __restrict__ pbias, float* __restrict__ out) {
    constexpr int PADW = KT * 16;
    constexpr int LDW  = PADW + 4;
    constexpr int R4   = PADW / 4;         // float4 per row
    constexpr int WNT  = NTSPLIT ? 1 : 2;
    uint32* bufH = bufA;
    uint32* bufL = bufA + 32 * LDW;
    int t  = blk % (TFR + 1);
    int b  = blk / (TFR + 1);
    int tf = (t == TFR) ? 0 : t;
    const float4* sH = (const float4*)(Ghi + (size_t)(b * TFR + tf) * 32 * PADW);
    const float4* sL = (const float4*)(Glo + (size_t)(b * TFR + tf) * 32 * PADW);
    for (int i = threadIdx.x; i < 32 * R4; i += 256) {
        int row = i / R4, c = i - row * R4;
        *(float4*)&bufH[row * LDW + 4 * c] = sH[i];
        *(float4*)&bufL[row * LDW + 4 * c] = sL[i];
    }
    __syncthreads();

    int lane = threadIdx.x & 63, w = threadIdx.x >> 6;
    int col = lane & 15, quad = lane >> 4;
    const u16* bufh = (const u16*)bufH;
    const u16* bufl = (const u16*)bufL;

    f32x4 accB[WMT][WNT], accD[WMT][WNT];   // base rows m, derived rows m+N/2
    #pragma unroll
    for (int mi = 0; mi < WMT; ++mi)
        #pragma unroll
        for (int nj = 0; nj < WNT; ++nj) {
            f32x4 z = {0.f, 0.f, 0.f, 0.f};
            accB[mi][nj] = z; accD[mi][nj] = z;
        }
    for (int kt = 0; kt < KT; ++kt) {
        half8 bh[WNT], bl[WNT], bhm[WNT], blm[WNT];
        #pragma unroll
        for (int nj = 0; nj < WNT; ++nj) {
            int nt = NTSPLIT ? (w & 1) : nj;
            int ro = (nt * 16 + col) * (2 * LDW) + kt * 32 + quad * 8;
            bh[nj]  = *(const half8*)(bufh + ro);
            bl[nj]  = *(const half8*)(bufl + ro);
            bhm[nj] = flip_pm(bh[nj]);
            blm[nj] = flip_pm(bl[nj]);
        }
        #pragma unroll
        for (int mi = 0; mi < WMT; ++mi) {
            int mt = NTSPLIT ? (w >> 1) : (w * WMT + mi);
            half8 ah = ((const half8*)whi)[(mt * KT + kt) * 64 + lane];
            half8 al = ((const half8*)wlo)[(mt * KT + kt) * 64 + lane];
            #pragma unroll
            for (int nj = 0; nj < WNT; ++nj) {
                accB[mi][nj] = __builtin_amdgcn_mfma_f32_16x16x32_f16(ah, bh[nj],  accB[mi][nj], 0, 0, 0);
                accB[mi][nj] = __builtin_amdgcn_mfma_f32_16x16x32_f16(ah, bl[nj],  accB[mi][nj], 0, 0, 0);
                accB[mi][nj] = __builtin_amdgcn_mfma_f32_16x16x32_f16(al, bh[nj],  accB[mi][nj], 0, 0, 0);
                accD[mi][nj] = __builtin_amdgcn_mfma_f32_16x16x32_f16(ah, bhm[nj], accD[mi][nj], 0, 0, 0);
                accD[mi][nj] = __builtin_amdgcn_mfma_f32_16x16x32_f16(ah, blm[nj], accD[mi][nj], 0, 0, 0);
                accD[mi][nj] = __builtin_amdgcn_mfma_f32_16x16x32_f16(al, bhm[nj], accD[mi][nj], 0, 0, 0);
            }
        }
    }
    constexpr float UNSCALE = 1.0f / 32768.0f;   // 2^-15 (W*2^10, S*2^5)
    size_t bb = (size_t)b * TCO;
    #pragma unroll
    for (int mi = 0; mi < WMT; ++mi) {
        int mt = NTSPLIT ? (w >> 1) : (w * WMT + mi);
        #pragma unroll
        for (int hh = 0; hh < 2; ++hh) {
            int m  = mt * 16 + quad * 4 + hh * (N / 2);
            int l0 = t * N + m - N / 2;
            if ((unsigned)l0 < LL) {
                #pragma unroll
                for (int nj = 0; nj < WNT; ++nj) {
                    int nt = NTSPLIT ? (w & 1) : nj;
                    int chn = CH0 + nt * 16 + col;
                    float pb = pbias[chn];
                    f32x4 a = hh ? accD[mi][nj] : accB[mi][nj];
                    float4 v;
                    v.x = fmaxf(fmaf(a[0], UNSCALE, pb), 0.f);
                    v.y = fmaxf(fmaf(a[1], UNSCALE, pb), 0.f);
                    v.z = fmaxf(fmaf(a[2], UNSCALE, pb), 0.f);
                    v.w = fmaxf(fmaf(a[3], UNSCALE, pb), 0.f);
                    *(float4*)(out + (bb + chn) * LL + l0) = v;
                }
            }
        }
    }
}

__global__ __launch_bounds__(256)
void irfft_both_kernel(const uint32* __restrict__ Ghi1, const uint32* __restrict__ Glo1,
                       const uint32* __restrict__ Ghi0, const uint32* __restrict__ Glo0,
                       const u16* __restrict__ whi1, const u16* __restrict__ wlo1,
                       const u16* __restrict__ whi0, const u16* __restrict__ wlo0,
                       const float* __restrict__ pbias, float* __restrict__ out) {
    __shared__ __align__(16) uint32 buf[2 * 32 * (PW1 + 4)];   // 37.9 KB (head1 size)
    constexpr int NB1 = BB * (T1n + 1);    // 2112
    int blk = blockIdx.x;
    if (blk < NB1)
        irfft_body<256, F1n, T1n, 32, 9, 2, false>(blk, buf, Ghi1, Glo1, whi1, wlo1, pbias, out);
    else
        irfft_body<64, F0n, T0n, 0, 3, 1, true>(blk - NB1, buf, Ghi0, Glo0, whi0, wlo0, pbias, out);
}

extern "C" void kernel_launch(void* const* d_in, const int* in_sizes, int n_in,
                              void* d_out, int out_size, void* d_ws, size_t ws_size,
                              hipStream_t stream) {
    const float* x     = (const float*)d_in[0];
    const float* gam   = (const float*)d_in[1];
    const float* bet   = (const float*)d_in[2];
    const float* mkr   = (const float*)d_in[3];
    const float* mki   = (const float*)d_in[4];
    const float* mbr   = (const float*)d_in[5];
    const float* mbi   = (const float*)d_in[6];
    const float* fk0r  = (const float*)d_in[7];
    const float* fk0i  = (const float*)d_in[8];
    const float* fk1r  = (const float*)d_in[9];
    const float* fk1i  = (const float*)d_in[10];
    const float* pbias = (const float*)d_in[11];
    float* out = (float*)d_out;

    float2* p0   = (float2*)d_ws;                                   // 34.6 MB
    float2* p1   = p0 + (size_t)BB * T0n * CIN * F0n;               // 33.8 MB
    float4* bnp  = (float4*)(p1 + (size_t)BB * T1n * CIN * F1n);    // 2 KB
    float4* part = bnp + 2 * BB;                                    // 16 KB
    float4* fkq0 = part + 1024;                                     // 135 KB
    float4* fkq1 = fkq0 + 8 * F0n * 32;                             // 528 KB
    float2* fks0 = (float2*)(fkq1 + 8 * F1n * 32);                  // 8 KB
    float2* fks1 = fks0 + F0n * 32;                                 // 33 KB
    uint32* Ghi1 = (uint32*)(fks1 + F1n * 32);                      // 37.7 MB
    uint32* Glo1 = Ghi1 + (size_t)BB * T1n * 32 * PW1;              // 37.7 MB
    uint32* Ghi0 = Glo1 + (size_t)BB * T1n * 32 * PW1;              // 50.3 MB
    uint32* Glo0 = Ghi0 + (size_t)BB * T0n * 32 * PW0;              // 50.3 MB
    u16*    whi0 = (u16*)(Glo0 + (size_t)BB * T0n * 32 * PW0);      // 6 KB
    u16*    wlo0 = whi0 + 3072;
    u16*    whi1 = wlo0 + 3072;                                     // 72 KB
    u16*    wlo1 = whi1 + 36864;
    u16*    dhi0 = wlo1 + 36864;                                    // 10 KB
    u16*    dlo0 = dhi0 + 5120;
    u16*    dhi1 = dlo0 + 5120;                                     // 139 KB
    u16*    dlo1 = dhi1 + 69632;

    init_w_kernel<<<(3072 + 36864 + 255) / 256, 256, 0, stream>>>(whi0, wlo0, whi1, wlo1);
    init_d_kernel<<<(5120 + 69632 + 255) / 256, 256, 0, stream>>>(dhi0, dlo0, dhi1, dlo1);
    init_fk_kernel<<<(8 * (F0n + F1n) * 32 + (F0n + F1n) * 32 + 255) / 256, 256, 0, stream>>>(
        fk0r, fk0i, fk1r, fk1i, fkq0, fkq1, fks0, fks1);
    stft_mfma_kernel<64, F0n, 128, 5, 2, 2, 5, 1, true><<<BB * CIN, 256, 0, stream>>>(
        x, dhi0, dlo0, (float*)p0);
    stft_mfma_kernel<256, F1n, 32, 17, 8, 2, 5, 4, false><<<BB * CIN, 256, 0, stream>>>(
        x, dhi1, dlo1, (float*)p1);
    merge_kernel<<<(BB * T1n * CIN * F0n) / 256, 256, 0, stream>>>(p0, p1, mkr, mki, mbr, mbi);
    cbn_partial_kernel<<<1024, 256, 0, stream>>>(p0, p1, part);
    cbn_final_kernel<<<1, 128, 0, stream>>>(part, gam, bet, bnp);
    // per-head einsum launches (round-7 codegen), then one merged irfft launch
    einsum_kernel<F1n, T1n, 32, PW1><<<(PW1 / 8) * (T1n / 16) * BB, 256, 0, stream>>>(
        p1, fkq1, fks1, bnp, Ghi1, Glo1);
    einsum_kernel<F0n, T0n, 0, PW0><<<(PW0 / 8) * (T0n / 16) * BB, 256, 0, stream>>>(
        p0, fkq0, fks0, bnp, Ghi0, Glo0);
    constexpr int NBI = BB * (T1n + 1) + BB * (T0n + 1);             // 2112+8256
    irfft_both_kernel<<<NBI, 256, 0, stream>>>(
        Ghi1, Glo1, Ghi0, Glo0, whi1, wlo1, whi0, wlo0, pbias, out);
}

// Round 11
// 460.920 us; speedup vs baseline: 1.0579x; 1.0579x over previous
//
#include <hip/hip_runtime.h>
#include <math.h>

// Problem constants
#define BB   64
#define CIN  16
#define LL   8192
#define CO   32
#define TCO  64
constexpr int T0n = 128;   // frames for n=64
constexpr int T1n = 32;    // frames for n=256
constexpr int F0n = 33;
constexpr int F1n = 129;
constexpr int PS0 = 40;    // S row dwords, head0 (5 f-chunks of 8, >= F0n)
constexpr int PS1 = 136;   // S row dwords, head1 (17 f-chunks of 8, >= F1n)
constexpr int LW0 = 64;    // irfft LDS row dwords head0 (mult of 32 -> swizzle ok)
constexpr int LW1 = 160;   // irfft LDS row dwords head1

typedef unsigned int   uint32;
typedef unsigned short u16;
typedef __attribute__((ext_vector_type(8))) _Float16 half8;  // 8 f16 (4 VGPRs)
typedef __attribute__((ext_vector_type(4))) float    f32x4;  // MFMA accumulator
typedef __attribute__((ext_vector_type(4))) uint32   u32x4;

__device__ inline int imin(int a, int b) { return a < b ? a : b; }

__device__ inline uint32 pack2h(float a, float b) {
    _Float16 ha = (_Float16)a, hb = (_Float16)b;
    return ((uint32)(*(u16*)&hb) << 16) | (uint32)(*(u16*)&ha);
}

// sign-flip pattern (+,+,-,-,+,+,-,-) over a half8 B-frag: k2 = 8a+j -> f = 4a+(j>>1),
// (-1)^f over j flips j=2,3,6,7 = dwords 1 and 3.  Used for W row symmetry:
// W[m+N/2][k2] = (-1)^{f(k2)} * W[m][k2].  (correctness-proven, 468us run)
__device__ inline half8 flip_pm(half8 v) {
    u32x4 u;
    __builtin_memcpy(&u, &v, 16);
    u.y ^= 0x80008000u;
    u.w ^= 0x80008000u;
    half8 r;
    __builtin_memcpy(&r, &u, 16);
    return r;
}

// ---------------- STFT as GEMM: spec[t][j] = sum_k X[t][k] * D[k][j] -----------
template<int N, int F, int TFR, int NTILES, int KTT, int MT_W, int NT_W,
         int NT_STRIDE, bool MT_SPLIT>
__global__ __launch_bounds__(256)
void stft_mfma_kernel(const float* __restrict__ x,
                      const u16* __restrict__ dhi, const u16* __restrict__ dlo,
                      float* __restrict__ p) {
    constexpr int PADN = N + 8;            // +16B row pad -> 2-way LDS alias (free)
    __shared__ __align__(16) u16 Xhi[TFR * PADN];
    __shared__ __align__(16) u16 Xlo[TFR * PADN];
    int bc = blockIdx.x;                   // b*CIN + c
    const float* xrow = x + (size_t)bc * LL;

    // reflected edge (row 0, colk < N/2): scalar
    for (int i = threadIdx.x; i < N / 2; i += 256) {
        float v = xrow[N / 2 - i];
        _Float16 h = (_Float16)v;
        Xhi[i] = *(u16*)&h;
        _Float16 l = (_Float16)(v - (float)h);
        Xlo[i] = *(u16*)&l;
    }
    // bulk: float4 loads, uint2 LDS stores (G13 vectorization)
    for (int i4 = N / 8 + threadIdx.x; i4 < TFR * N / 4; i4 += 256) {
        int i = 4 * i4;
        int row = i / N, colk = i - row * N;   // N pow2 -> shifts
        float4 v = *(const float4*)&xrow[i - N / 2];
        _Float16 h0 = (_Float16)v.x, h1 = (_Float16)v.y,
                 h2 = (_Float16)v.z, h3 = (_Float16)v.w;
        uint2 hv, lv;
        hv.x = ((uint32)(*(u16*)&h1) << 16) | (uint32)(*(u16*)&h0);
        hv.y = ((uint32)(*(u16*)&h3) << 16) | (uint32)(*(u16*)&h2);
        lv.x = pack2h(v.x - (float)h0, v.y - (float)h1);
        lv.y = pack2h(v.z - (float)h2, v.w - (float)h3);
        *(uint2*)&Xhi[row * PADN + colk] = hv;
        *(uint2*)&Xlo[row * PADN + colk] = lv;
    }
    __syncthreads();

    int lane = threadIdx.x & 63, w = threadIdx.x >> 6;
    int col = lane & 15, quad = lane >> 4;
    f32x4 acc[MT_W][NT_W];
    #pragma unroll
    for (int mi = 0; mi < MT_W; ++mi)
        #pragma unroll
        for (int nj = 0; nj < NT_W; ++nj) {
            f32x4 z = {0.f, 0.f, 0.f, 0.f};
            acc[mi][nj] = z;
        }

    for (int kt = 0; kt < KTT; ++kt) {
        half8 ah[MT_W], al[MT_W];
        #pragma unroll
        for (int mi = 0; mi < MT_W; ++mi) {
            int mt = MT_SPLIT ? (w * MT_W + mi) : mi;
            int t  = mt * 16 + col;
            ah[mi] = *(const half8*)&Xhi[t * PADN + kt * 32 + quad * 8];
            al[mi] = *(const half8*)&Xlo[t * PADN + kt * 32 + quad * 8];
        }
        #pragma unroll
        for (int nj = 0; nj < NT_W; ++nj) {
            int nt = MT_SPLIT ? nj : (w + nj * NT_STRIDE);
            if (nt < NTILES) {
                half8 bh = ((const half8*)dhi)[(nt * KTT + kt) * 64 + lane];
                half8 bl = ((const half8*)dlo)[(nt * KTT + kt) * 64 + lane];
                #pragma unroll
                for (int mi = 0; mi < MT_W; ++mi) {
                    acc[mi][nj] = __builtin_amdgcn_mfma_f32_16x16x32_f16(ah[mi], bh, acc[mi][nj], 0, 0, 0);
                    acc[mi][nj] = __builtin_amdgcn_mfma_f32_16x16x32_f16(ah[mi], bl, acc[mi][nj], 0, 0, 0);
                    acc[mi][nj] = __builtin_amdgcn_mfma_f32_16x16x32_f16(al[mi], bh, acc[mi][nj], 0, 0, 0);
                }
            }
        }
    }

    int b = bc / CIN, c = bc % CIN;
    #pragma unroll
    for (int mi = 0; mi < MT_W; ++mi) {
        int mt = MT_SPLIT ? (w * MT_W + mi) : mi;
        #pragma unroll
        for (int nj = 0; nj < NT_W; ++nj) {
            int nt = MT_SPLIT ? nj : (w + nj * NT_STRIDE);
            if (nt < NTILES) {
                int j = nt * 16 + col;
                if (j < 2 * F) {
                    int t0 = mt * 16 + quad * 4;
                    f32x4 a = acc[mi][nj];
                    #pragma unroll
                    for (int r = 0; r < 4; ++r) {
                        p[(((size_t)b * TFR + t0 + r) * CIN + c) * (2 * F) + j] = a[r];
                    }
                }
            }
        }
    }
}

// ---------------- init: STFT D tables, B-fragment order, split fp16 ------------
__global__ __launch_bounds__(256)
void init_d_kernel(u16* __restrict__ dhi0, u16* __restrict__ dlo0,
                   u16* __restrict__ dhi1, u16* __restrict__ dlo1) {
    int idx = blockIdx.x * 256 + threadIdx.x;
    constexpr int SZ0 = 5 * 2 * 64 * 8;    // 5120
    constexpr int SZ1 = 17 * 8 * 64 * 8;   // 69632
    int N, F, KTT, id; u16 *dh, *dl;
    if (idx < SZ0)            { N = 64;  F = F0n; KTT = 2; dh = dhi0; dl = dlo0; id = idx; }
    else if (idx < SZ0 + SZ1) { N = 256; F = F1n; KTT = 8; dh = dhi1; dl = dlo1; id = idx - SZ0; }
    else return;
    int jj   = id & 7;
    int lane = (id >> 3) & 63;
    int rest = id >> 9;
    int kt   = rest % KTT;
    int nt   = rest / KTT;
    int j = nt * 16 + (lane & 15);
    int k = kt * 32 + (lane >> 4) * 8 + jj;
    float v = 0.f;
    if (j < 2 * F) {
        int f = j >> 1;
        int u = (f * k) % N;
        double th = 6.283185307179586476925286766559 * (double)u / (double)N;
        v = (float)((j & 1) ? -sin(th) : cos(th));
    }
    _Float16 h = (_Float16)v;
    _Float16 l = (_Float16)(v - (float)h);
    dh[id] = *(u16*)&h;
    dl[id] = *(u16*)&l;
}

// ---------------- merge (attention over 4 sub-frames), in-place into p1 --------
__global__ __launch_bounds__(256)
void merge_kernel(const float2* __restrict__ p0, float2* __restrict__ p1,
                  const float* __restrict__ mkr, const float* __restrict__ mki,
                  const float* __restrict__ mbr, const float* __restrict__ mbi) {
    int idx = blockIdx.x * 256 + threadIdx.x;
    const int total = BB * T1n * CIN * F0n;
    if (idx >= total) return;
    int f0 = idx % F0n; int r1 = idx / F0n;
    int c  = r1 % CIN;  int r2 = r1 / CIN;
    int t1 = r2 % T1n;  int b  = r2 / T1n;
    float2 pm[4];
    #pragma unroll
    for (int r = 0; r < 4; ++r) {
        int t = t1 * 4 + r;
        pm[r] = p0[(((size_t)b * T0n + t) * CIN + c) * F0n + f0];
    }
    float mag[4], mx = -1e30f;
    #pragma unroll
    for (int s = 0; s < 4; ++s) {
        float atr = mbr[s], ati = mbi[s];
        #pragma unroll
        for (int r = 0; r < 4; ++r) {
            float kr = mkr[r * 4 + s], ki = mki[r * 4 + s];
            atr = fmaf(pm[r].x, kr, atr); atr = fmaf(-pm[r].y, ki, atr);
            ati = fmaf(pm[r].x, ki, ati); ati = fmaf(pm[r].y, kr, ati);
        }
        mag[s] = sqrtf(atr * atr + ati * ati);
        mx = fmaxf(mx, mag[s]);
    }
    float se = 0.f;
    #pragma unroll
    for (int s = 0; s < 4; ++s) { mag[s] = expf(mag[s] - mx); se += mag[s]; }
    float inv = 4.0f / se;                 // RATIO / sum
    float mr = 0.f, mi = 0.f;
    #pragma unroll
    for (int r = 0; r < 4; ++r) { mr = fmaf(pm[r].x, mag[r], mr); mi = fmaf(pm[r].y, mag[r], mi); }
    p1[(((size_t)b * T1n + t1) * CIN + c) * F1n + 4 * f0] = make_float2(mr * inv, mi * inv);
}

// ---------------- complex batch-norm stats, two-stage ---------------------------
__global__ __launch_bounds__(256)
void cbn_partial_kernel(const float2* __restrict__ p0, const float2* __restrict__ p1,
                        float4* __restrict__ part) {
    int blk  = blockIdx.x;                 // head*512 + b*8 + c8
    int c8   = blk & 7;
    int b    = (blk >> 3) & 63;
    int head = blk >> 9;
    int Nel  = head ? (T1n * CIN * F1n) : (T0n * CIN * F0n);
    const float2* base = head ? (p1 + (size_t)b * (T1n * CIN * F1n))
                              : (p0 + (size_t)b * (T0n * CIN * F0n));
    int chunk = (Nel + 7) / 8;
    int i0 = c8 * chunk, i1 = imin(i0 + chunk, Nel);
    float sr = 0.f, si = 0.f, s2 = 0.f;
    for (int i = i0 + threadIdx.x; i < i1; i += 256) {
        float2 v = base[i];
        sr += v.x; si += v.y;
        s2 = fmaf(v.x, v.x, s2); s2 = fmaf(v.y, v.y, s2);
    }
    __shared__ float red[3][256];
    red[0][threadIdx.x] = sr; red[1][threadIdx.x] = si; red[2][threadIdx.x] = s2;
    __syncthreads();
    for (int off = 128; off > 0; off >>= 1) {
        if (threadIdx.x < off) {
            red[0][threadIdx.x] += red[0][threadIdx.x + off];
            red[1][threadIdx.x] += red[1][threadIdx.x + off];
            red[2][threadIdx.x] += red[2][threadIdx.x + off];
        }
        __syncthreads();
    }
    if (threadIdx.x == 0)
        part[blk] = make_float4(red[0][0], red[1][0], red[2][0], 0.f);
}

__global__ __launch_bounds__(128)
void cbn_final_kernel(const float4* __restrict__ part,
                      const float* __restrict__ gamma, const float* __restrict__ beta,
                      float4* __restrict__ bn) {
    int hb = threadIdx.x;                  // 0..127 = head*64 + b
    float sr = 0.f, si = 0.f, s2 = 0.f;
    #pragma unroll
    for (int c = 0; c < 8; ++c) {
        float4 v = part[hb * 8 + c];
        sr += v.x; si += v.y; s2 += v.z;
    }
    int head = hb >> 6;
    int Nel  = head ? (T1n * CIN * F1n) : (T0n * CIN * F0n);
    float invN = 1.f / (float)Nel;
    float mur = sr * invN, mui = si * invN;
    float var = s2 * invN - mur * mur - mui * mui;
    float g = gamma[hb] * rsqrtf(var + 1e-5f);
    bn[hb] = make_float4(g, beta[hb] - mur * g, -mui * g, 0.f);
}

// ---------------- init: irfft twiddle matrix (HALF rows m < N/2), split fp16 ---
__global__ __launch_bounds__(256)
void init_w_kernel(u16* __restrict__ whi0, u16* __restrict__ wlo0,
                   u16* __restrict__ whi1, u16* __restrict__ wlo1) {
    int idx = blockIdx.x * 256 + threadIdx.x;
    constexpr int SZ0 = 2 * 3 * 64 * 8;    // 3072
    constexpr int SZ1 = 8 * 9 * 64 * 8;    // 36864
    int N, F, KT, id; u16 *dh, *dl;
    if (idx < SZ0)            { N = 64;  F = F0n; KT = 3; dh = whi0; dl = wlo0; id = idx; }
    else if (idx < SZ0 + SZ1) { N = 256; F = F1n; KT = 9; dh = whi1; dl = wlo1; id = idx - SZ0; }
    else return;
    int j    = id & 7;
    int lane = (id >> 3) & 63;
    int rest = id >> 9;
    int kt   = rest % KT;
    int mt   = rest / KT;
    int m  = mt * 16 + (lane & 15);        // m < N/2 only
    int k2 = kt * 32 + (lane >> 4) * 8 + j;
    float v = 0.f;
    if (k2 < 2 * F) {
        int f = k2 >> 1;
        double scale = (f == 0 || f == F - 1) ? (1024.0 / N) : (2048.0 / N);
        int u = (m * f) % N;
        double th = 6.283185307179586476925286766559 * (double)u / (double)N;
        v = (float)((k2 & 1) ? (-scale * sin(th)) : (scale * cos(th)));
    }
    _Float16 h = (_Float16)v;
    _Float16 l = (_Float16)(v - (float)h);
    dh[id] = *(u16*)&h;
    dl[id] = *(u16*)&l;
}

// ---------------- init: fk tables, layout i = o*F + f --------------------------
__global__ __launch_bounds__(256)
void init_fk_kernel(const float* __restrict__ r0, const float* __restrict__ i0,
                    const float* __restrict__ r1, const float* __restrict__ i1,
                    float4* __restrict__ q0, float4* __restrict__ q1,
                    float2* __restrict__ s0, float2* __restrict__ s1) {
    int idx = blockIdx.x * 256 + threadIdx.x;
    constexpr int NQ0 = 8 * F0n * 32;   // 8448
    constexpr int NQ1 = 8 * F1n * 32;   // 33024
    constexpr int NS0 = F0n * 32;       // 1056
    constexpr int NS1 = F1n * 32;       // 4128
    if (idx < NQ0) {
        int id = idx;
        int c2 = id / (F0n * 32); int rem = id % (F0n * 32);
        int o = rem / F0n, f = rem % F0n;
        int s = (f * CIN + 2 * c2) * CO + o;
        q0[id] = make_float4(r0[s], i0[s], r0[s + CO], i0[s + CO]);
    } else if (idx < NQ0 + NQ1) {
        int id = idx - NQ0;
        int c2 = id / (F1n * 32); int rem = id % (F1n * 32);
        int o = rem / F1n, f = rem % F1n;
        int s = (f * CIN + 2 * c2) * CO + o;
        q1[id] = make_float4(r1[s], i1[s], r1[s + CO], i1[s + CO]);
    } else if (idx < NQ0 + NQ1 + NS0) {
        int id = idx - NQ0 - NQ1;
        int o = id / F0n, f = id % F0n;
        float sr = 0.f, si = 0.f;
        for (int ci = 0; ci < CIN; ++ci) {
            int s = (f * CIN + ci) * CO + o;
            sr += r0[s]; si += i0[s];
        }
        s0[id] = make_float2(sr, si);
    } else if (idx < NQ0 + NQ1 + NS0 + NS1) {
        int id = idx - NQ0 - NQ1 - NS0;
        int o = id / F1n, f = id % F1n;
        float sr = 0.f, si = 0.f;
        for (int ci = 0; ci < CIN; ++ci) {
            int s = (f * CIN + ci) * CO + o;
            sr += r1[s]; si += i1[s];
        }
        s1[id] = make_float2(sr, si);
    }
}

// ---------------- einsum: weights-in-VGPR, t-chunked, per-head launches --------
// (rule #19: merging heads into one kernel demoted the kk[8] VGPR cache).
// f-chunks cover PS (>= F, mult of 8); threads with f >= F store zeros so the
// irfft stage is a pure float4 copy.  S row stride = PS dwords.
template<int F, int TFR, int CH0, int PS>
__global__ __launch_bounds__(256)
void einsum_kernel(const float2* __restrict__ p, const float4* __restrict__ fkq,
                   const float2* __restrict__ fks, const float4* __restrict__ bn,
                   uint32* __restrict__ Ghi, uint32* __restrict__ Glo) {
    constexpr int FCH = 8, TCH = 16;
    constexpr int FCO  = F * 32;
    constexpr int NFCH = PS / FCH;
    constexpr int NTC  = TFR / TCH;
    __shared__ float2 xs[TCH][CIN][FCH];
    int blk  = blockIdx.x;
    int fch  = blk % NFCH;
    int rest = blk / NFCH;
    int tc   = rest % NTC;
    int b    = rest / NTC;
    int t0   = tc * TCH;
    int f0   = fch * FCH;
    int o    = threadIdx.x >> 3;       // 0..31
    int fl   = threadIdx.x & 7;        // 0..7
    int f    = f0 + fl;
    bool valid = f < F;
    int fc = valid ? f : F - 1;
    float4 kk[8];
    #pragma unroll
    for (int c2 = 0; c2 < 8; ++c2) kk[c2] = fkq[c2 * FCO + o * F + fc];  // coalesced
    float2 fv = fks[o * F + fc];
    float4 par = bn[(CH0 ? 1 : 0) * BB + b];   // (g, t_re, t_im, -)
    float base_re = fmaf(par.y, fv.x, -par.z * fv.y);
    float base_im = fmaf(par.y, fv.y,  par.z * fv.x);

    const float2* pb = p + (size_t)(b * TFR + t0) * CIN * F;
    for (int i = threadIdx.x; i < TCH * CIN * FCH; i += 256) {
        int fi = i & 7;                // FCH = 8
        int r  = i >> 3;               // t'*CIN + ci
        int ff = f0 + fi;
        ((float2*)xs)[i] = (ff < F) ? pb[(size_t)r * F + ff] : make_float2(0.f, 0.f);
    }
    __syncthreads();
    for (int tp = 0; tp < TCH; ++tp) {
        float re = 0.f, im = 0.f;
        #pragma unroll
        for (int c2 = 0; c2 < 8; ++c2) {
            float2 xa = xs[tp][2 * c2][fl];        // LDS broadcast
            float2 xb = xs[tp][2 * c2 + 1][fl];
            float4 kkc = kk[c2];
            re = fmaf(xa.x, kkc.x, re); re = fmaf(-xa.y, kkc.y, re);
            im = fmaf(xa.x, kkc.y, im); im = fmaf(xa.y, kkc.x, im);
            re = fmaf(xb.x, kkc.z, re); re = fmaf(-xb.y, kkc.w, re);
            im = fmaf(xb.x, kkc.w, im); im = fmaf(xb.y, kkc.z, im);
        }
        uint32 hv = 0, lv = 0;
        if (valid) {
            float res = fmaf(par.x, re, base_re) * 32.f;
            float ims = fmaf(par.x, im, base_im) * 32.f;
            _Float16 rh = (_Float16)res; _Float16 rl = (_Float16)(res - (float)rh);
            _Float16 ih = (_Float16)ims; _Float16 il = (_Float16)(ims - (float)ih);
            hv = ((uint32)(*(u16*)&ih) << 16) | (uint32)(*(u16*)&rh);
            lv = ((uint32)(*(u16*)&il) << 16) | (uint32)(*(u16*)&rl);
        }
        size_t d = ((size_t)(b * TFR + t0 + tp) * 32 + o) * PS + f;
        Ghi[d] = hv;
        Glo[d] = lv;
    }
}

// ---------------- irfft: per-frame blocks, per-head launch, XOR-swizzled LDS ---
// Per-head kernels (round-9 lesson: merged launch made head0 carry head1's LDS).
// LDS row stride LDSW dwords (mult of 32) with XOR swizzle: row-dword j lives at
// j ^ ((row&7)*4).  Write side XORs the float4 base (multiple-of-4 key keeps the
// 4 dwords contiguous); read side must use the SAME involution.
// *** Round-10 crash fix: the B-frag read offset kt*32+quad*8 is in U16 units;
// *** round 10 indexed the dword array with it (OOB past the LDS alloc -> fault).
// *** Correct: u16 pointer, row stride 2*LDSW, XOR key (col&7)*8 (u16 units).
// Stage = float4 copy of PS dwords/row + float4 zero of [PS, LDSW).
template<int N, int F, int TFR, int CH0, int KT, int PS, int LDSW, int WMT, bool NTSPLIT>
__global__ __launch_bounds__(256)
void irfft_kernel(const uint32* __restrict__ Ghi, const uint32* __restrict__ Glo,
                  const u16* __restrict__ whi, const u16* __restrict__ wlo,
                  const float* __restrict__ pbias, float* __restrict__ out) {
    static_assert(LDSW % 32 == 0 && PS % 4 == 0 && KT * 16 <= LDSW, "geom");
    constexpr int R4C = PS / 4;            // copy float4 per row
    constexpr int Z4  = (LDSW - PS) / 4;   // zero float4 per row
    constexpr int WNT = NTSPLIT ? 1 : 2;
    __shared__ __align__(16) uint32 buf[2 * 32 * LDSW];
    uint32* bufH = buf;
    uint32* bufL = buf + 32 * LDSW;

    int t  = blockIdx.x % (TFR + 1);
    int b  = blockIdx.x / (TFR + 1);
    int tf = (t == TFR) ? 0 : t;
    const float4* sH = (const float4*)(Ghi + (size_t)(b * TFR + tf) * 32 * PS);
    const float4* sL = (const float4*)(Glo + (size_t)(b * TFR + tf) * 32 * PS);
    for (int i = threadIdx.x; i < 32 * R4C; i += 256) {
        int row = i / R4C, c4 = i - row * R4C;
        int dst = row * LDSW + ((4 * c4) ^ ((row & 7) * 4));
        *(float4*)&bufH[dst] = sH[i];
        *(float4*)&bufL[dst] = sL[i];
    }
    for (int i = threadIdx.x; i < 32 * Z4; i += 256) {
        int row = i / Z4, c4 = R4C + (i - row * Z4);
        int dst = row * LDSW + ((4 * c4) ^ ((row & 7) * 4));
        float4 z = make_float4(0.f, 0.f, 0.f, 0.f);
        *(float4*)&bufH[dst] = z;
        *(float4*)&bufL[dst] = z;
    }
    __syncthreads();

    int lane = threadIdx.x & 63, w = threadIdx.x >> 6;
    int col = lane & 15, quad = lane >> 4;
    const u16* bufh = (const u16*)bufH;    // reads in u16 units (row = 2*LDSW u16)
    const u16* bufl = (const u16*)bufL;

    f32x4 accB[WMT][WNT], accD[WMT][WNT];   // base rows m, derived rows m+N/2
    #pragma unroll
    for (int mi = 0; mi < WMT; ++mi)
        #pragma unroll
        for (int nj = 0; nj < WNT; ++nj) {
            f32x4 z = {0.f, 0.f, 0.f, 0.f};
            accB[mi][nj] = z; accD[mi][nj] = z;
        }
    int swzR = (col & 7) * 8;              // u16 units; row&7 == col&7 (rows = nt*16+col)
    for (int kt = 0; kt < KT; ++kt) {
        half8 bh[WNT], bl[WNT], bhm[WNT], blm[WNT];
        #pragma unroll
        for (int nj = 0; nj < WNT; ++nj) {
            int nt = NTSPLIT ? (w & 1) : nj;
            int R  = nt * 16 + col;
            int ro = R * (2 * LDSW) + ((kt * 32 + quad * 8) ^ swzR);
            bh[nj]  = *(const half8*)&bufh[ro];
            bl[nj]  = *(const half8*)&bufl[ro];
            bhm[nj] = flip_pm(bh[nj]);
            blm[nj] = flip_pm(bl[nj]);
        }
        #pragma unroll
        for (int mi = 0; mi < WMT; ++mi) {
            int mt = NTSPLIT ? (w >> 1) : (w * WMT + mi);
            half8 ah = ((const half8*)whi)[(mt * KT + kt) * 64 + lane];
            half8 al = ((const half8*)wlo)[(mt * KT + kt) * 64 + lane];
            #pragma unroll
            for (int nj = 0; nj < WNT; ++nj) {
                accB[mi][nj] = __builtin_amdgcn_mfma_f32_16x16x32_f16(ah, bh[nj],  accB[mi][nj], 0, 0, 0);
                accB[mi][nj] = __builtin_amdgcn_mfma_f32_16x16x32_f16(ah, bl[nj],  accB[mi][nj], 0, 0, 0);
                accB[mi][nj] = __builtin_amdgcn_mfma_f32_16x16x32_f16(al, bh[nj],  accB[mi][nj], 0, 0, 0);
                accD[mi][nj] = __builtin_amdgcn_mfma_f32_16x16x32_f16(ah, bhm[nj], accD[mi][nj], 0, 0, 0);
                accD[mi][nj] = __builtin_amdgcn_mfma_f32_16x16x32_f16(ah, blm[nj], accD[mi][nj], 0, 0, 0);
                accD[mi][nj] = __builtin_amdgcn_mfma_f32_16x16x32_f16(al, bhm[nj], accD[mi][nj], 0, 0, 0);
            }
        }
    }
    constexpr float UNSCALE = 1.0f / 32768.0f;   // 2^-15 (W*2^10, S*2^5)
    size_t bb = (size_t)b * TCO;
    #pragma unroll
    for (int mi = 0; mi < WMT; ++mi) {
        int mt = NTSPLIT ? (w >> 1) : (w * WMT + mi);
        #pragma unroll
        for (int hh = 0; hh < 2; ++hh) {
            int m  = mt * 16 + quad * 4 + hh * (N / 2);
            int l0 = t * N + m - N / 2;
            if ((unsigned)l0 < LL) {
                #pragma unroll
                for (int nj = 0; nj < WNT; ++nj) {
                    int nt = NTSPLIT ? (w & 1) : nj;
                    int chn = CH0 + nt * 16 + col;
                    float pb = pbias[chn];
                    f32x4 a = hh ? accD[mi][nj] : accB[mi][nj];
                    float4 v;
                    v.x = fmaxf(fmaf(a[0], UNSCALE, pb), 0.f);
                    v.y = fmaxf(fmaf(a[1], UNSCALE, pb), 0.f);
                    v.z = fmaxf(fmaf(a[2], UNSCALE, pb), 0.f);
                    v.w = fmaxf(fmaf(a[3], UNSCALE, pb), 0.f);
                    *(float4*)(out + (bb + chn) * LL + l0) = v;
                }
            }
        }
    }
}

extern "C" void kernel_launch(void* const* d_in, const int* in_sizes, int n_in,
                              void* d_out, int out_size, void* d_ws, size_t ws_size,
                              hipStream_t stream) {
    const float* x     = (const float*)d_in[0];
    const float* gam   = (const float*)d_in[1];
    const float* bet   = (const float*)d_in[2];
    const float* mkr   = (const float*)d_in[3];
    const float* mki   = (const float*)d_in[4];
    const float* mbr   = (const float*)d_in[5];
    const float* mbi   = (const float*)d_in[6];
    const float* fk0r  = (const float*)d_in[7];
    const float* fk0i  = (const float*)d_in[8];
    const float* fk1r  = (const float*)d_in[9];
    const float* fk1i  = (const float*)d_in[10];
    const float* pbias = (const float*)d_in[11];
    float* out = (float*)d_out;

    float2* p0   = (float2*)d_ws;                                   // 34.6 MB
    float2* p1   = p0 + (size_t)BB * T0n * CIN * F0n;               // 33.8 MB
    float4* bnp  = (float4*)(p1 + (size_t)BB * T1n * CIN * F1n);    // 2 KB
    float4* part = bnp + 2 * BB;                                    // 16 KB
    float4* fkq0 = part + 1024;                                     // 135 KB
    float4* fkq1 = fkq0 + 8 * F0n * 32;                             // 528 KB
    float2* fks0 = (float2*)(fkq1 + 8 * F1n * 32);                  // 8 KB
    float2* fks1 = fks0 + F0n * 32;                                 // 33 KB
    uint32* Ghi1 = (uint32*)(fks1 + F1n * 32);                      // 35.7 MB
    uint32* Glo1 = Ghi1 + (size_t)BB * T1n * 32 * PS1;              // 35.7 MB
    uint32* Ghi0 = Glo1 + (size_t)BB * T1n * 32 * PS1;              // 41.9 MB
    uint32* Glo0 = Ghi0 + (size_t)BB * T0n * 32 * PS0;              // 41.9 MB
    u16*    whi0 = (u16*)(Glo0 + (size_t)BB * T0n * 32 * PS0);      // 6 KB
    u16*    wlo0 = whi0 + 3072;
    u16*    whi1 = wlo0 + 3072;                                     // 72 KB
    u16*    wlo1 = whi1 + 36864;
    u16*    dhi0 = wlo1 + 36864;                                    // 10 KB
    u16*    dlo0 = dhi0 + 5120;
    u16*    dhi1 = dlo0 + 5120;                                     // 139 KB
    u16*    dlo1 = dhi1 + 69632;

    init_w_kernel<<<(3072 + 36864 + 255) / 256, 256, 0, stream>>>(whi0, wlo0, whi1, wlo1);
    init_d_kernel<<<(5120 + 69632 + 255) / 256, 256, 0, stream>>>(dhi0, dlo0, dhi1, dlo1);
    init_fk_kernel<<<(8 * (F0n + F1n) * 32 + (F0n + F1n) * 32 + 255) / 256, 256, 0, stream>>>(
        fk0r, fk0i, fk1r, fk1i, fkq0, fkq1, fks0, fks1);
    stft_mfma_kernel<64, F0n, 128, 5, 2, 2, 5, 1, true><<<BB * CIN, 256, 0, stream>>>(
        x, dhi0, dlo0, (float*)p0);
    stft_mfma_kernel<256, F1n, 32, 17, 8, 2, 5, 4, false><<<BB * CIN, 256, 0, stream>>>(
        x, dhi1, dlo1, (float*)p1);
    merge_kernel<<<(BB * T1n * CIN * F0n) / 256, 256, 0, stream>>>(p0, p1, mkr, mki, mbr, mbi);
    cbn_partial_kernel<<<1024, 256, 0, stream>>>(p0, p1, part);
    cbn_final_kernel<<<1, 128, 0, stream>>>(part, gam, bet, bnp);
    // per-head einsum + per-head irfft (separate kernels: own LDS size + regalloc)
    einsum_kernel<F1n, T1n, 32, PS1><<<(PS1 / 8) * (T1n / 16) * BB, 256, 0, stream>>>(
        p1, fkq1, fks1, bnp, Ghi1, Glo1);
    irfft_kernel<256, F1n, T1n, 32, 9, PS1, LW1, 2, false><<<BB * (T1n + 1), 256, 0, stream>>>(
        Ghi1, Glo1, whi1, wlo1, pbias, out);
    einsum_kernel<F0n, T0n, 0, PS0><<<(PS0 / 8) * (T0n / 16) * BB, 256, 0, stream>>>(
        p0, fkq0, fks0, bnp, Ghi0, Glo0);
    irfft_kernel<64, F0n, T0n, 0, 3, PS0, LW0, 1, true><<<BB * (T0n + 1), 256, 0, stream>>>(
        Ghi0, Glo0, whi0, wlo0, pbias, out);
}

// Round 12
// 454.084 us; speedup vs baseline: 1.0738x; 1.0151x over previous
//
#include <hip/hip_runtime.h>
#include <math.h>

// Problem constants
#define BB   64
#define CIN  16
#define LL   8192
#define CO   32
#define TCO  64
constexpr int T0n = 128;   // frames for n=64
constexpr int T1n = 32;    // frames for n=256
constexpr int F0n = 33;
constexpr int F1n = 129;
constexpr int PS0 = 48;    // S row dwords, head0 (3 f-chunks of 16, = KT0*16)
constexpr int PS1 = 144;   // S row dwords, head1 (9 f-chunks of 16, = KT1*16)
constexpr int LW0 = 64;    // irfft LDS row dwords head0 (mult of 32 -> swizzle ok)
constexpr int LW1 = 160;   // irfft LDS row dwords head1

typedef unsigned int   uint32;
typedef unsigned short u16;
typedef __attribute__((ext_vector_type(8))) _Float16 half8;  // 8 f16 (4 VGPRs)
typedef __attribute__((ext_vector_type(4))) float    f32x4;  // MFMA accumulator
typedef __attribute__((ext_vector_type(4))) uint32   u32x4;

__device__ inline int imin(int a, int b) { return a < b ? a : b; }

__device__ inline uint32 pack2h(float a, float b) {
    _Float16 ha = (_Float16)a, hb = (_Float16)b;
    return ((uint32)(*(u16*)&hb) << 16) | (uint32)(*(u16*)&ha);
}

// sign-flip pattern (+,+,-,-,+,+,-,-) over a half8 B-frag: k2 = 8a+j -> f = 4a+(j>>1),
// (-1)^f over j flips j=2,3,6,7 = dwords 1 and 3.  Used for W row symmetry:
// W[m+N/2][k2] = (-1)^{f(k2)} * W[m][k2].  (correctness-proven, 468us run)
__device__ inline half8 flip_pm(half8 v) {
    u32x4 u;
    __builtin_memcpy(&u, &v, 16);
    u.y ^= 0x80008000u;
    u.w ^= 0x80008000u;
    half8 r;
    __builtin_memcpy(&r, &u, 16);
    return r;
}

// ---------------- STFT as GEMM: spec[t][j] = sum_k X[t][k] * D[k][j] -----------
template<int N, int F, int TFR, int NTILES, int KTT, int MT_W, int NT_W,
         int NT_STRIDE, bool MT_SPLIT>
__global__ __launch_bounds__(256)
void stft_mfma_kernel(const float* __restrict__ x,
                      const u16* __restrict__ dhi, const u16* __restrict__ dlo,
                      float* __restrict__ p) {
    constexpr int PADN = N + 8;            // +16B row pad -> 2-way LDS alias (free)
    __shared__ __align__(16) u16 Xhi[TFR * PADN];
    __shared__ __align__(16) u16 Xlo[TFR * PADN];
    int bc = blockIdx.x;                   // b*CIN + c
    const float* xrow = x + (size_t)bc * LL;

    // reflected edge (row 0, colk < N/2): scalar
    for (int i = threadIdx.x; i < N / 2; i += 256) {
        float v = xrow[N / 2 - i];
        _Float16 h = (_Float16)v;
        Xhi[i] = *(u16*)&h;
        _Float16 l = (_Float16)(v - (float)h);
        Xlo[i] = *(u16*)&l;
    }
    // bulk: float4 loads, uint2 LDS stores (G13 vectorization)
    for (int i4 = N / 8 + threadIdx.x; i4 < TFR * N / 4; i4 += 256) {
        int i = 4 * i4;
        int row = i / N, colk = i - row * N;   // N pow2 -> shifts
        float4 v = *(const float4*)&xrow[i - N / 2];
        _Float16 h0 = (_Float16)v.x, h1 = (_Float16)v.y,
                 h2 = (_Float16)v.z, h3 = (_Float16)v.w;
        uint2 hv, lv;
        hv.x = ((uint32)(*(u16*)&h1) << 16) | (uint32)(*(u16*)&h0);
        hv.y = ((uint32)(*(u16*)&h3) << 16) | (uint32)(*(u16*)&h2);
        lv.x = pack2h(v.x - (float)h0, v.y - (float)h1);
        lv.y = pack2h(v.z - (float)h2, v.w - (float)h3);
        *(uint2*)&Xhi[row * PADN + colk] = hv;
        *(uint2*)&Xlo[row * PADN + colk] = lv;
    }
    __syncthreads();

    int lane = threadIdx.x & 63, w = threadIdx.x >> 6;
    int col = lane & 15, quad = lane >> 4;
    f32x4 acc[MT_W][NT_W];
    #pragma unroll
    for (int mi = 0; mi < MT_W; ++mi)
        #pragma unroll
        for (int nj = 0; nj < NT_W; ++nj) {
            f32x4 z = {0.f, 0.f, 0.f, 0.f};
            acc[mi][nj] = z;
        }

    for (int kt = 0; kt < KTT; ++kt) {
        half8 ah[MT_W], al[MT_W];
        #pragma unroll
        for (int mi = 0; mi < MT_W; ++mi) {
            int mt = MT_SPLIT ? (w * MT_W + mi) : mi;
            int t  = mt * 16 + col;
            ah[mi] = *(const half8*)&Xhi[t * PADN + kt * 32 + quad * 8];
            al[mi] = *(const half8*)&Xlo[t * PADN + kt * 32 + quad * 8];
        }
        #pragma unroll
        for (int nj = 0; nj < NT_W; ++nj) {
            int nt = MT_SPLIT ? nj : (w + nj * NT_STRIDE);
            if (nt < NTILES) {
                half8 bh = ((const half8*)dhi)[(nt * KTT + kt) * 64 + lane];
                half8 bl = ((const half8*)dlo)[(nt * KTT + kt) * 64 + lane];
                #pragma unroll
                for (int mi = 0; mi < MT_W; ++mi) {
                    acc[mi][nj] = __builtin_amdgcn_mfma_f32_16x16x32_f16(ah[mi], bh, acc[mi][nj], 0, 0, 0);
                    acc[mi][nj] = __builtin_amdgcn_mfma_f32_16x16x32_f16(ah[mi], bl, acc[mi][nj], 0, 0, 0);
                    acc[mi][nj] = __builtin_amdgcn_mfma_f32_16x16x32_f16(al[mi], bh, acc[mi][nj], 0, 0, 0);
                }
            }
        }
    }

    int b = bc / CIN, c = bc % CIN;
    #pragma unroll
    for (int mi = 0; mi < MT_W; ++mi) {
        int mt = MT_SPLIT ? (w * MT_W + mi) : mi;
        #pragma unroll
        for (int nj = 0; nj < NT_W; ++nj) {
            int nt = MT_SPLIT ? nj : (w + nj * NT_STRIDE);
            if (nt < NTILES) {
                int j = nt * 16 + col;
                if (j < 2 * F) {
                    int t0 = mt * 16 + quad * 4;
                    f32x4 a = acc[mi][nj];
                    #pragma unroll
                    for (int r = 0; r < 4; ++r) {
                        p[(((size_t)b * TFR + t0 + r) * CIN + c) * (2 * F) + j] = a[r];
                    }
                }
            }
        }
    }
}

// ---------------- init: STFT D tables, B-fragment order, split fp16 ------------
__global__ __launch_bounds__(256)
void init_d_kernel(u16* __restrict__ dhi0, u16* __restrict__ dlo0,
                   u16* __restrict__ dhi1, u16* __restrict__ dlo1) {
    int idx = blockIdx.x * 256 + threadIdx.x;
    constexpr int SZ0 = 5 * 2 * 64 * 8;    // 5120
    constexpr int SZ1 = 17 * 8 * 64 * 8;   // 69632
    int N, F, KTT, id; u16 *dh, *dl;
    if (idx < SZ0)            { N = 64;  F = F0n; KTT = 2; dh = dhi0; dl = dlo0; id = idx; }
    else if (idx < SZ0 + SZ1) { N = 256; F = F1n; KTT = 8; dh = dhi1; dl = dlo1; id = idx - SZ0; }
    else return;
    int jj   = id & 7;
    int lane = (id >> 3) & 63;
    int rest = id >> 9;
    int kt   = rest % KTT;
    int nt   = rest / KTT;
    int j = nt * 16 + (lane & 15);
    int k = kt * 32 + (lane >> 4) * 8 + jj;
    float v = 0.f;
    if (j < 2 * F) {
        int f = j >> 1;
        int u = (f * k) % N;
        double th = 6.283185307179586476925286766559 * (double)u / (double)N;
        v = (float)((j & 1) ? -sin(th) : cos(th));
    }
    _Float16 h = (_Float16)v;
    _Float16 l = (_Float16)(v - (float)h);
    dh[id] = *(u16*)&h;
    dl[id] = *(u16*)&l;
}

// ---------------- merge (attention over 4 sub-frames), in-place into p1 --------
__global__ __launch_bounds__(256)
void merge_kernel(const float2* __restrict__ p0, float2* __restrict__ p1,
                  const float* __restrict__ mkr, const float* __restrict__ mki,
                  const float* __restrict__ mbr, const float* __restrict__ mbi) {
    int idx = blockIdx.x * 256 + threadIdx.x;
    const int total = BB * T1n * CIN * F0n;
    if (idx >= total) return;
    int f0 = idx % F0n; int r1 = idx / F0n;
    int c  = r1 % CIN;  int r2 = r1 / CIN;
    int t1 = r2 % T1n;  int b  = r2 / T1n;
    float2 pm[4];
    #pragma unroll
    for (int r = 0; r < 4; ++r) {
        int t = t1 * 4 + r;
        pm[r] = p0[(((size_t)b * T0n + t) * CIN + c) * F0n + f0];
    }
    float mag[4], mx = -1e30f;
    #pragma unroll
    for (int s = 0; s < 4; ++s) {
        float atr = mbr[s], ati = mbi[s];
        #pragma unroll
        for (int r = 0; r < 4; ++r) {
            float kr = mkr[r * 4 + s], ki = mki[r * 4 + s];
            atr = fmaf(pm[r].x, kr, atr); atr = fmaf(-pm[r].y, ki, atr);
            ati = fmaf(pm[r].x, ki, ati); ati = fmaf(pm[r].y, kr, ati);
        }
        mag[s] = sqrtf(atr * atr + ati * ati);
        mx = fmaxf(mx, mag[s]);
    }
    float se = 0.f;
    #pragma unroll
    for (int s = 0; s < 4; ++s) { mag[s] = expf(mag[s] - mx); se += mag[s]; }
    float inv = 4.0f / se;                 // RATIO / sum
    float mr = 0.f, mi = 0.f;
    #pragma unroll
    for (int r = 0; r < 4; ++r) { mr = fmaf(pm[r].x, mag[r], mr); mi = fmaf(pm[r].y, mag[r], mi); }
    p1[(((size_t)b * T1n + t1) * CIN + c) * F1n + 4 * f0] = make_float2(mr * inv, mi * inv);
}

// ---------------- complex batch-norm stats, two-stage ---------------------------
__global__ __launch_bounds__(256)
void cbn_partial_kernel(const float2* __restrict__ p0, const float2* __restrict__ p1,
                        float4* __restrict__ part) {
    int blk  = blockIdx.x;                 // head*512 + b*8 + c8
    int c8   = blk & 7;
    int b    = (blk >> 3) & 63;
    int head = blk >> 9;
    int Nel  = head ? (T1n * CIN * F1n) : (T0n * CIN * F0n);
    const float2* base = head ? (p1 + (size_t)b * (T1n * CIN * F1n))
                              : (p0 + (size_t)b * (T0n * CIN * F0n));
    int chunk = (Nel + 7) / 8;
    int i0 = c8 * chunk, i1 = imin(i0 + chunk, Nel);
    float sr = 0.f, si = 0.f, s2 = 0.f;
    for (int i = i0 + threadIdx.x; i < i1; i += 256) {
        float2 v = base[i];
        sr += v.x; si += v.y;
        s2 = fmaf(v.x, v.x, s2); s2 = fmaf(v.y, v.y, s2);
    }
    __shared__ float red[3][256];
    red[0][threadIdx.x] = sr; red[1][threadIdx.x] = si; red[2][threadIdx.x] = s2;
    __syncthreads();
    for (int off = 128; off > 0; off >>= 1) {
        if (threadIdx.x < off) {
            red[0][threadIdx.x] += red[0][threadIdx.x + off];
            red[1][threadIdx.x] += red[1][threadIdx.x + off];
            red[2][threadIdx.x] += red[2][threadIdx.x + off];
        }
        __syncthreads();
    }
    if (threadIdx.x == 0)
        part[blk] = make_float4(red[0][0], red[1][0], red[2][0], 0.f);
}

__global__ __launch_bounds__(128)
void cbn_final_kernel(const float4* __restrict__ part,
                      const float* __restrict__ gamma, const float* __restrict__ beta,
                      float4* __restrict__ bn) {
    int hb = threadIdx.x;                  // 0..127 = head*64 + b
    float sr = 0.f, si = 0.f, s2 = 0.f;
    #pragma unroll
    for (int c = 0; c < 8; ++c) {
        float4 v = part[hb * 8 + c];
        sr += v.x; si += v.y; s2 += v.z;
    }
    int head = hb >> 6;
    int Nel  = head ? (T1n * CIN * F1n) : (T0n * CIN * F0n);
    float invN = 1.f / (float)Nel;
    float mur = sr * invN, mui = si * invN;
    float var = s2 * invN - mur * mur - mui * mui;
    float g = gamma[hb] * rsqrtf(var + 1e-5f);
    bn[hb] = make_float4(g, beta[hb] - mur * g, -mui * g, 0.f);
}

// ---------------- init: irfft twiddle matrix (HALF rows m < N/2), split fp16 ---
__global__ __launch_bounds__(256)
void init_w_kernel(u16* __restrict__ whi0, u16* __restrict__ wlo0,
                   u16* __restrict__ whi1, u16* __restrict__ wlo1) {
    int idx = blockIdx.x * 256 + threadIdx.x;
    constexpr int SZ0 = 2 * 3 * 64 * 8;    // 3072
    constexpr int SZ1 = 8 * 9 * 64 * 8;    // 36864
    int N, F, KT, id; u16 *dh, *dl;
    if (idx < SZ0)            { N = 64;  F = F0n; KT = 3; dh = whi0; dl = wlo0; id = idx; }
    else if (idx < SZ0 + SZ1) { N = 256; F = F1n; KT = 9; dh = whi1; dl = wlo1; id = idx - SZ0; }
    else return;
    int j    = id & 7;
    int lane = (id >> 3) & 63;
    int rest = id >> 9;
    int kt   = rest % KT;
    int mt   = rest / KT;
    int m  = mt * 16 + (lane & 15);        // m < N/2 only
    int k2 = kt * 32 + (lane >> 4) * 8 + j;
    float v = 0.f;
    if (k2 < 2 * F) {
        int f = k2 >> 1;
        double scale = (f == 0 || f == F - 1) ? (1024.0 / N) : (2048.0 / N);
        int u = (m * f) % N;
        double th = 6.283185307179586476925286766559 * (double)u / (double)N;
        v = (float)((k2 & 1) ? (-scale * sin(th)) : (scale * cos(th)));
    }
    _Float16 h = (_Float16)v;
    _Float16 l = (_Float16)(v - (float)h);
    dh[id] = *(u16*)&h;
    dl[id] = *(u16*)&l;
}

// ---------------- init: fk tables, layout i = o*F + f --------------------------
__global__ __launch_bounds__(256)
void init_fk_kernel(const float* __restrict__ r0, const float* __restrict__ i0,
                    const float* __restrict__ r1, const float* __restrict__ i1,
                    float4* __restrict__ q0, float4* __restrict__ q1,
                    float2* __restrict__ s0, float2* __restrict__ s1) {
    int idx = blockIdx.x * 256 + threadIdx.x;
    constexpr int NQ0 = 8 * F0n * 32;   // 8448
    constexpr int NQ1 = 8 * F1n * 32;   // 33024
    constexpr int NS0 = F0n * 32;       // 1056
    constexpr int NS1 = F1n * 32;       // 4128
    if (idx < NQ0) {
        int id = idx;
        int c2 = id / (F0n * 32); int rem = id % (F0n * 32);
        int o = rem / F0n, f = rem % F0n;
        int s = (f * CIN + 2 * c2) * CO + o;
        q0[id] = make_float4(r0[s], i0[s], r0[s + CO], i0[s + CO]);
    } else if (idx < NQ0 + NQ1) {
        int id = idx - NQ0;
        int c2 = id / (F1n * 32); int rem = id % (F1n * 32);
        int o = rem / F1n, f = rem % F1n;
        int s = (f * CIN + 2 * c2) * CO + o;
        q1[id] = make_float4(r1[s], i1[s], r1[s + CO], i1[s + CO]);
    } else if (idx < NQ0 + NQ1 + NS0) {
        int id = idx - NQ0 - NQ1;
        int o = id / F0n, f = id % F0n;
        float sr = 0.f, si = 0.f;
        for (int ci = 0; ci < CIN; ++ci) {
            int s = (f * CIN + ci) * CO + o;
            sr += r0[s]; si += i0[s];
        }
        s0[id] = make_float2(sr, si);
    } else if (idx < NQ0 + NQ1 + NS0 + NS1) {
        int id = idx - NQ0 - NQ1 - NS0;
        int o = id / F1n, f = id % F1n;
        float sr = 0.f, si = 0.f;
        for (int ci = 0; ci < CIN; ++ci) {
            int s = (f * CIN + ci) * CO + o;
            sr += r1[s]; si += i1[s];
        }
        s1[id] = make_float2(sr, si);
    }
}

// ---------------- einsum: weights-in-VGPR, FCH=16 (64B coalesced S stores) -----
// Round-11 evidence: FCH=8 stores were 32B segments -> WRITE_SIZE 2.0x actual
// (HBM RMW).  FCH=16: 16 consecutive lanes write 16 consecutive dwords = 64B
// burst-aligned segments.  oc in {0,1} selects o half (16 o x 16 f per block);
// x-slice read twice per (fch,tc,b) but L3-hot.  f >= F stores zeros (pad) so
// the irfft stage stays a pure float4 copy.  S row stride = PS dwords.
// (rule #19: per-head kernels; never merge heads behind a runtime branch.)
template<int F, int TFR, int CH0, int PS>
__global__ __launch_bounds__(256)
void einsum_kernel(const float2* __restrict__ p, const float4* __restrict__ fkq,
                   const float2* __restrict__ fks, const float4* __restrict__ bn,
                   uint32* __restrict__ Ghi, uint32* __restrict__ Glo) {
    constexpr int FCH = 16, TCH = 16;
    constexpr int FCO  = F * 32;
    constexpr int NFCH = PS / FCH;
    constexpr int NTC  = TFR / TCH;
    static_assert(PS % FCH == 0, "PS mult of 16");
    __shared__ float2 xs[TCH][CIN][FCH];   // 32 KB
    int blk  = blockIdx.x;
    int fch  = blk % NFCH;
    int rest = blk / NFCH;
    int oc   = rest & 1;  rest >>= 1;
    int tc   = rest % NTC;
    int b    = rest / NTC;
    int t0   = tc * TCH;
    int f0   = fch * FCH;
    int o    = oc * 16 + (threadIdx.x >> 4);   // 0..31
    int fl   = threadIdx.x & 15;               // 0..15
    int f    = f0 + fl;
    bool valid = f < F;
    int fc = valid ? f : F - 1;
    float4 kk[8];
    #pragma unroll
    for (int c2 = 0; c2 < 8; ++c2) kk[c2] = fkq[c2 * FCO + o * F + fc];  // 256B runs
    float2 fv = fks[o * F + fc];
    float4 par = bn[(CH0 ? 1 : 0) * BB + b];   // (g, t_re, t_im, -)
    float base_re = fmaf(par.y, fv.x, -par.z * fv.y);
    float base_im = fmaf(par.y, fv.y,  par.z * fv.x);

    const float2* pb = p + (size_t)(b * TFR + t0) * CIN * F;
    for (int i = threadIdx.x; i < TCH * CIN * FCH; i += 256) {
        int fi = i & 15;               // FCH = 16
        int r  = i >> 4;               // t'*CIN + ci
        int ff = f0 + fi;
        ((float2*)xs)[i] = (ff < F) ? pb[(size_t)r * F + ff] : make_float2(0.f, 0.f);
    }
    __syncthreads();
    for (int tp = 0; tp < TCH; ++tp) {
        float re = 0.f, im = 0.f;
        #pragma unroll
        for (int c2 = 0; c2 < 8; ++c2) {
            float2 xa = xs[tp][2 * c2][fl];        // LDS broadcast (4 lanes/addr)
            float2 xb = xs[tp][2 * c2 + 1][fl];
            float4 kkc = kk[c2];
            re = fmaf(xa.x, kkc.x, re); re = fmaf(-xa.y, kkc.y, re);
            im = fmaf(xa.x, kkc.y, im); im = fmaf(xa.y, kkc.x, im);
            re = fmaf(xb.x, kkc.z, re); re = fmaf(-xb.y, kkc.w, re);
            im = fmaf(xb.x, kkc.w, im); im = fmaf(xb.y, kkc.z, im);
        }
        uint32 hv = 0, lv = 0;
        if (valid) {
            float res = fmaf(par.x, re, base_re) * 32.f;
            float ims = fmaf(par.x, im, base_im) * 32.f;
            _Float16 rh = (_Float16)res; _Float16 rl = (_Float16)(res - (float)rh);
            _Float16 ih = (_Float16)ims; _Float16 il = (_Float16)(ims - (float)ih);
            hv = ((uint32)(*(u16*)&ih) << 16) | (uint32)(*(u16*)&rh);
            lv = ((uint32)(*(u16*)&il) << 16) | (uint32)(*(u16*)&rl);
        }
        size_t d = ((size_t)(b * TFR + t0 + tp) * 32 + o) * PS + f;
        Ghi[d] = hv;                   // 64B segments per 16 lanes
        Glo[d] = lv;
    }
}

// ---------------- irfft: per-frame blocks, per-head launch, XOR-swizzled LDS ---
// Per-head kernels (round-9 lesson: merged launch made head0 carry head1's LDS).
// LDS row stride LDSW dwords (mult of 32) with XOR swizzle: row-dword j lives at
// j ^ ((row&7)*4).  Write side XORs the float4 base (multiple-of-4 key keeps the
// 4 dwords contiguous); read side uses the SAME involution in U16 units:
// u16 row stride 2*LDSW, XOR key (col&7)*8.  (round-10 crash: dword/u16 mixup.)
// Stage = float4 copy of PS dwords/row + float4 zero of [PS, LDSW).
template<int N, int F, int TFR, int CH0, int KT, int PS, int LDSW, int WMT, bool NTSPLIT>
__global__ __launch_bounds__(256)
void irfft_kernel(const uint32* __restrict__ Ghi, const uint32* __restrict__ Glo,
                  const u16* __restrict__ whi, const u16* __restrict__ wlo,
                  const float* __restrict__ pbias, float* __restrict__ out) {
    static_assert(LDSW % 32 == 0 && PS % 4 == 0 && KT * 16 <= LDSW, "geom");
    constexpr int R4C = PS / 4;            // copy float4 per row
    constexpr int Z4  = (LDSW - PS) / 4;   // zero float4 per row
    constexpr int WNT = NTSPLIT ? 1 : 2;
    __shared__ __align__(16) uint32 buf[2 * 32 * LDSW];
    uint32* bufH = buf;
    uint32* bufL = buf + 32 * LDSW;

    int t  = blockIdx.x % (TFR + 1);
    int b  = blockIdx.x / (TFR + 1);
    int tf = (t == TFR) ? 0 : t;
    const float4* sH = (const float4*)(Ghi + (size_t)(b * TFR + tf) * 32 * PS);
    const float4* sL = (const float4*)(Glo + (size_t)(b * TFR + tf) * 32 * PS);
    for (int i = threadIdx.x; i < 32 * R4C; i += 256) {
        int row = i / R4C, c4 = i - row * R4C;
        int dst = row * LDSW + ((4 * c4) ^ ((row & 7) * 4));
        *(float4*)&bufH[dst] = sH[i];
        *(float4*)&bufL[dst] = sL[i];
    }
    for (int i = threadIdx.x; i < 32 * Z4; i += 256) {
        int row = i / Z4, c4 = R4C + (i - row * Z4);
        int dst = row * LDSW + ((4 * c4) ^ ((row & 7) * 4));
        float4 z = make_float4(0.f, 0.f, 0.f, 0.f);
        *(float4*)&bufH[dst] = z;
        *(float4*)&bufL[dst] = z;
    }
    __syncthreads();

    int lane = threadIdx.x & 63, w = threadIdx.x >> 6;
    int col = lane & 15, quad = lane >> 4;
    const u16* bufh = (const u16*)bufH;    // reads in u16 units (row = 2*LDSW u16)
    const u16* bufl = (const u16*)bufL;

    f32x4 accB[WMT][WNT], accD[WMT][WNT];   // base rows m, derived rows m+N/2
    #pragma unroll
    for (int mi = 0; mi < WMT; ++mi)
        #pragma unroll
        for (int nj = 0; nj < WNT; ++nj) {
            f32x4 z = {0.f, 0.f, 0.f, 0.f};
            accB[mi][nj] = z; accD[mi][nj] = z;
        }
    int swzR = (col & 7) * 8;              // u16 units; row&7 == col&7 (rows = nt*16+col)
    for (int kt = 0; kt < KT; ++kt) {
        half8 bh[WNT], bl[WNT], bhm[WNT], blm[WNT];
        #pragma unroll
        for (int nj = 0; nj < WNT; ++nj) {
            int nt = NTSPLIT ? (w & 1) : nj;
            int R  = nt * 16 + col;
            int ro = R * (2 * LDSW) + ((kt * 32 + quad * 8) ^ swzR);
            bh[nj]  = *(const half8*)&bufh[ro];
            bl[nj]  = *(const half8*)&bufl[ro];
            bhm[nj] = flip_pm(bh[nj]);
            blm[nj] = flip_pm(bl[nj]);
        }
        #pragma unroll
        for (int mi = 0; mi < WMT; ++mi) {
            int mt = NTSPLIT ? (w >> 1) : (w * WMT + mi);
            half8 ah = ((const half8*)whi)[(mt * KT + kt) * 64 + lane];
            half8 al = ((const half8*)wlo)[(mt * KT + kt) * 64 + lane];
            #pragma unroll
            for (int nj = 0; nj < WNT; ++nj) {
                accB[mi][nj] = __builtin_amdgcn_mfma_f32_16x16x32_f16(ah, bh[nj],  accB[mi][nj], 0, 0, 0);
                accB[mi][nj] = __builtin_amdgcn_mfma_f32_16x16x32_f16(ah, bl[nj],  accB[mi][nj], 0, 0, 0);
                accB[mi][nj] = __builtin_amdgcn_mfma_f32_16x16x32_f16(al, bh[nj],  accB[mi][nj], 0, 0, 0);
                accD[mi][nj] = __builtin_amdgcn_mfma_f32_16x16x32_f16(ah, bhm[nj], accD[mi][nj], 0, 0, 0);
                accD[mi][nj] = __builtin_amdgcn_mfma_f32_16x16x32_f16(ah, blm[nj], accD[mi][nj], 0, 0, 0);
                accD[mi][nj] = __builtin_amdgcn_mfma_f32_16x16x32_f16(al, bhm[nj], accD[mi][nj], 0, 0, 0);
            }
        }
    }
    constexpr float UNSCALE = 1.0f / 32768.0f;   // 2^-15 (W*2^10, S*2^5)
    size_t bb = (size_t)b * TCO;
    #pragma unroll
    for (int mi = 0; mi < WMT; ++mi) {
        int mt = NTSPLIT ? (w >> 1) : (w * WMT + mi);
        #pragma unroll
        for (int hh = 0; hh < 2; ++hh) {
            int m  = mt * 16 + quad * 4 + hh * (N / 2);
            int l0 = t * N + m - N / 2;
            if ((unsigned)l0 < LL) {
                #pragma unroll
                for (int nj = 0; nj < WNT; ++nj) {
                    int nt = NTSPLIT ? (w & 1) : nj;
                    int chn = CH0 + nt * 16 + col;
                    float pb = pbias[chn];
                    f32x4 a = hh ? accD[mi][nj] : accB[mi][nj];
                    float4 v;
                    v.x = fmaxf(fmaf(a[0], UNSCALE, pb), 0.f);
                    v.y = fmaxf(fmaf(a[1], UNSCALE, pb), 0.f);
                    v.z = fmaxf(fmaf(a[2], UNSCALE, pb), 0.f);
                    v.w = fmaxf(fmaf(a[3], UNSCALE, pb), 0.f);
                    *(float4*)(out + (bb + chn) * LL + l0) = v;
                }
            }
        }
    }
}

extern "C" void kernel_launch(void* const* d_in, const int* in_sizes, int n_in,
                              void* d_out, int out_size, void* d_ws, size_t ws_size,
                              hipStream_t stream) {
    const float* x     = (const float*)d_in[0];
    const float* gam   = (const float*)d_in[1];
    const float* bet   = (const float*)d_in[2];
    const float* mkr   = (const float*)d_in[3];
    const float* mki   = (const float*)d_in[4];
    const float* mbr   = (const float*)d_in[5];
    const float* mbi   = (const float*)d_in[6];
    const float* fk0r  = (const float*)d_in[7];
    const float* fk0i  = (const float*)d_in[8];
    const float* fk1r  = (const float*)d_in[9];
    const float* fk1i  = (const float*)d_in[10];
    const float* pbias = (const float*)d_in[11];
    float* out = (float*)d_out;

    float2* p0   = (float2*)d_ws;                                   // 34.6 MB
    float2* p1   = p0 + (size_t)BB * T0n * CIN * F0n;               // 33.8 MB
    float4* bnp  = (float4*)(p1 + (size_t)BB * T1n * CIN * F1n);    // 2 KB
    float4* part = bnp + 2 * BB;                                    // 16 KB
    float4* fkq0 = part + 1024;                                     // 135 KB
    float4* fkq1 = fkq0 + 8 * F0n * 32;                             // 528 KB
    float2* fks0 = (float2*)(fkq1 + 8 * F1n * 32);                  // 8 KB
    float2* fks1 = fks0 + F0n * 32;                                 // 33 KB
    uint32* Ghi1 = (uint32*)(fks1 + F1n * 32);                      // 37.7 MB
    uint32* Glo1 = Ghi1 + (size_t)BB * T1n * 32 * PS1;              // 37.7 MB
    uint32* Ghi0 = Glo1 + (size_t)BB * T1n * 32 * PS1;              // 50.3 MB
    uint32* Glo0 = Ghi0 + (size_t)BB * T0n * 32 * PS0;              // 50.3 MB
    u16*    whi0 = (u16*)(Glo0 + (size_t)BB * T0n * 32 * PS0);      // 6 KB
    u16*    wlo0 = whi0 + 3072;
    u16*    whi1 = wlo0 + 3072;                                     // 72 KB
    u16*    wlo1 = whi1 + 36864;
    u16*    dhi0 = wlo1 + 36864;                                    // 10 KB
    u16*    dlo0 = dhi0 + 5120;
    u16*    dhi1 = dlo0 + 5120;                                     // 139 KB
    u16*    dlo1 = dhi1 + 69632;

    init_w_kernel<<<(3072 + 36864 + 255) / 256, 256, 0, stream>>>(whi0, wlo0, whi1, wlo1);
    init_d_kernel<<<(5120 + 69632 + 255) / 256, 256, 0, stream>>>(dhi0, dlo0, dhi1, dlo1);
    init_fk_kernel<<<(8 * (F0n + F1n) * 32 + (F0n + F1n) * 32 + 255) / 256, 256, 0, stream>>>(
        fk0r, fk0i, fk1r, fk1i, fkq0, fkq1, fks0, fks1);
    stft_mfma_kernel<64, F0n, 128, 5, 2, 2, 5, 1, true><<<BB * CIN, 256, 0, stream>>>(
        x, dhi0, dlo0, (float*)p0);
    stft_mfma_kernel<256, F1n, 32, 17, 8, 2, 5, 4, false><<<BB * CIN, 256, 0, stream>>>(
        x, dhi1, dlo1, (float*)p1);
    merge_kernel<<<(BB * T1n * CIN * F0n) / 256, 256, 0, stream>>>(p0, p1, mkr, mki, mbr, mbi);
    cbn_partial_kernel<<<1024, 256, 0, stream>>>(p0, p1, part);
    cbn_final_kernel<<<1, 128, 0, stream>>>(part, gam, bet, bnp);
    // per-head einsum + per-head irfft (separate kernels: own LDS size + regalloc)
    einsum_kernel<F1n, T1n, 32, PS1><<<(PS1 / 16) * 2 * (T1n / 16) * BB, 256, 0, stream>>>(
        p1, fkq1, fks1, bnp, Ghi1, Glo1);
    irfft_kernel<256, F1n, T1n, 32, 9, PS1, LW1, 2, false><<<BB * (T1n + 1), 256, 0, stream>>>(
        Ghi1, Glo1, whi1, wlo1, pbias, out);
    einsum_kernel<F0n, T0n, 0, PS0><<<(PS0 / 16) * 2 * (T0n / 16) * BB, 256, 0, stream>>>(
        p0, fkq0, fks0, bnp, Ghi0, Glo0);
    irfft_kernel<64, F0n, T0n, 0, 3, PS0, LW0, 1, true><<<BB * (T0n + 1), 256, 0, stream>>>(
        Ghi0, Glo0, whi0, wlo0, pbias, out);
}